// Round 6
// baseline (65.262 us; speedup 1.0000x reference)
//
#include <hip/hip_runtime.h>

// VQ-VAE quantizer forward — R16: 2-chunk software pipeline, fence-free.
//   inputs  [B=8, C=64, T=16, H=32, W=32] fp32   (layout: b*C*THW + c*THW + r)
//   codebook[K=512, C=64] fp32
// outputs: q_z [B,C,T,H,W] fp32, vq_loss, commitment_loss (concat flat)
//
// dist(p,k) = ||e_k||^2 - 2*x_p.e_k. Block builds the whole codebook (bf16,
// pre-scaled by -2, XOR-swizzled) + fp32 norms in LDS. MFMA C-init = ||e||^2
// => acc IS the distance. 9-bit code packed into mantissa LSBs => argmin is
// pure f32 min. Loss via ||e-x||^2 = ||x||^2 + d_best.
//
// R15 post-mortem: fused finalize's __threadfence() = device-scope release =
// L2 writeback per block x512 => +20 us (vq_main 46-52 us, VGPR 88, WRITE
// exact => body was fine). R13b/R14's regressions were fence + spills, so the
// 2-chunk pipeline concept was never cleanly measured. R16 tests it clean:
//  - 256 blocks x 256 thr (1/CU, 4 waves), 512 pos/block in TWO 256-pos
//    chunks; ONE xv[16] reg buffer (64 VGPR) reused: chunk0 loads -> cb build
//    covers latency -> convert0 -> barrier (drains chunk0+cb only) -> issue
//    chunk1 loads (sched_barrier pins issue) -> scan0/epi0 hide chunk1's HBM
//    stream -> convert1 -> scan1/epi1. Store burst of chunk0 overlaps scan1.
//  - separate trivial finalize kernel (R12 structure): NO atomics, NO fences,
//    NO memset. Regular cached x loads (R12-proven), NT q stores (R4-proven).

#define K_CODES 512
#define NCH     64
#define THW     16384
#define NELEM   8388608
#define NBLK    256

typedef __attribute__((ext_vector_type(8))) short bf16x8;
typedef __attribute__((ext_vector_type(4))) float f32x4;

__device__ __forceinline__ unsigned short f32_bf16(float f) {
    unsigned u = __float_as_uint(f);
    u += 0x7FFFu + ((u >> 16) & 1u);          // round-to-nearest-even
    return (unsigned short)(u >> 16);
}

struct AFrag { bf16x8 a[4][2]; };   // [tile tt][K-half]

// Scan 512 codes for one 256-pos chunk + argmin + idx publish + q epilogue.
// Returns per-lane sd (sum of 16 group-min distances, replicated x16/group).
__device__ __forceinline__ float scan_chunk(
        const AFrag& af,
        const unsigned char* __restrict__ lds_cb,
        const float* __restrict__ lds_norm,
        int* __restrict__ lds_idx,
        const float* __restrict__ cb,
        float* __restrict__ oq,
        int w, int g, int r15, int tid) {
    float best[4][4];
    #pragma unroll
    for (int tt = 0; tt < 4; ++tt)
        #pragma unroll
        for (int i = 0; i < 4; ++i) best[tt][i] = 3.4e38f;

    const int swz = (r15 & 7) << 4;
    const unsigned char* pb0 = lds_cb + r15 * 128 + ((g * 16) ^ swz);
    const unsigned char* pb1 = lds_cb + r15 * 128 + ((64 + g * 16) ^ swz);
    #pragma unroll
    for (int f = 0; f < 32; ++f) {
        const bf16x8 b0 = *(const bf16x8*)(pb0 + f * 2048);
        const bf16x8 b1 = *(const bf16x8*)(pb1 + f * 2048);
        const float nrm = lds_norm[f * 16 + r15];
        const unsigned code = (unsigned)(f * 16 + r15);   // lane's B-column
        #pragma unroll
        for (int tt = 0; tt < 4; ++tt) {
            f32x4 acc = {nrm, nrm, nrm, nrm};
            acc = __builtin_amdgcn_mfma_f32_16x16x32_bf16(af.a[tt][0], b0, acc, 0, 0, 0);
            acc = __builtin_amdgcn_mfma_f32_16x16x32_bf16(af.a[tt][1], b1, acc, 0, 0, 0);
            #pragma unroll
            for (int i = 0; i < 4; ++i) {   // acc[i]: pos rw+4*(4g+i)+tt
                const float pkv = __uint_as_float(
                    (__float_as_uint(acc[i]) & ~511u) | code);
                best[tt][i] = fminf(best[tt][i], pkv);
            }
        }
    }

    // wave-local argmin (reduce over r15 = code axis)
    float sd = 0.f;
    int   idxs[4][4];
    #pragma unroll
    for (int tt = 0; tt < 4; ++tt) {
        #pragma unroll
        for (int i = 0; i < 4; ++i) {
            float v = best[tt][i];
            #pragma unroll
            for (int off = 8; off; off >>= 1) v = fminf(v, __shfl_xor(v, off));
            sd += v;                                // replicated x16 per group
            idxs[tt][i] = (int)(__float_as_uint(v) & 511u);
        }
    }
    if (r15 == 0) {                   // same-wave RAW only (no barrier needed)
        #pragma unroll
        for (int tt = 0; tt < 4; ++tt)
            #pragma unroll
            for (int i = 0; i < 4; ++i)
                lds_idx[w * 64 + 16 * g + 4 * i + tt] = idxs[tt][i];
    }

    // epilogue: lane = one position; q from fp32 cb (L2-hot); NT stores
    const int bc = lds_idx[tid];
    const f32x4* crow = (const f32x4*)(cb + (size_t)bc * NCH);
    #pragma unroll
    for (int jj = 0; jj < 16; ++jj) {
        const f32x4 e = crow[jj];
        const size_t c0 = (size_t)(jj * 4) * THW;
        __builtin_nontemporal_store(e[0], oq + c0);
        __builtin_nontemporal_store(e[1], oq + c0 + THW);
        __builtin_nontemporal_store(e[2], oq + c0 + 2 * THW);
        __builtin_nontemporal_store(e[3], oq + c0 + 3 * THW);
    }
    return sd;
}

__global__ __launch_bounds__(256) void vq_main(
        const float* __restrict__ x,
        const float* __restrict__ cb,
        float* __restrict__ out,
        float* __restrict__ partials) {
    __shared__ __align__(16) unsigned char lds_cb[65536];   // bf16(-2e), swizzled
    __shared__ __align__(16) float lds_norm[K_CODES];
    __shared__ int lds_idx[256];

    const int tid  = threadIdx.x;
    const int lane = tid & 63;
    const int w    = tid >> 6;       // wave 0..3
    const int g    = lane >> 4;      // 16-lane group 0..3
    const int r15  = lane & 15;

    const int blk   = blockIdx.x;
    const int b     = blk >> 5;                 // batch (32 blocks per batch)
    const int rbase = (blk & 31) << 9;          // 512 positions per block
    const float* xb = x + (size_t)b * (NCH * THW);
    const int pos0  = rbase + w * 64 + 4 * r15; // chunk0 lane base position

    // ---- chunk0 x loads: f32x4; 16 lanes x 16B = 256B contiguous ----
    f32x4 xv[16];
    #pragma unroll
    for (int kf = 0; kf < 2; ++kf)
        #pragma unroll
        for (int j = 0; j < 8; ++j)
            xv[kf * 8 + j] = *(const f32x4*)(
                xb + (size_t)(kf * 32 + g * 8 + j) * THW + pos0);

    // ---- build FULL codebook in LDS (16 rounds; covers chunk0 latency):
    // thread t owns logical 16B chunk j8=t&7 of code row r=(t>>3)+32*rr,
    // stored at physical chunk j8^(r&7) => swizzled, matches scan map. ----
    #pragma unroll
    for (int rr = 0; rr < 16; ++rr) {
        const int r  = (tid >> 3) + (rr << 5);
        const int j8 = tid & 7;
        const f32x4* cr = (const f32x4*)(cb + r * NCH + j8 * 8);
        const f32x4 e0 = cr[0];
        const f32x4 e1 = cr[1];
        float s = e0[0] * e0[0];
        s = fmaf(e0[1], e0[1], s); s = fmaf(e0[2], e0[2], s); s = fmaf(e0[3], e0[3], s);
        s = fmaf(e1[0], e1[0], s); s = fmaf(e1[1], e1[1], s); s = fmaf(e1[2], e1[2], s);
        s = fmaf(e1[3], e1[3], s);
        s += __shfl_xor(s, 1); s += __shfl_xor(s, 2); s += __shfl_xor(s, 4);
        if (j8 == 0) lds_norm[r] = s;          // ||e_r||^2 (unscaled)
        bf16x8 pk;
        pk[0] = (short)f32_bf16(-2.f * e0[0]);
        pk[1] = (short)f32_bf16(-2.f * e0[1]);
        pk[2] = (short)f32_bf16(-2.f * e0[2]);
        pk[3] = (short)f32_bf16(-2.f * e0[3]);
        pk[4] = (short)f32_bf16(-2.f * e1[0]);
        pk[5] = (short)f32_bf16(-2.f * e1[1]);
        pk[6] = (short)f32_bf16(-2.f * e1[2]);
        pk[7] = (short)f32_bf16(-2.f * e1[3]);
        *(bf16x8*)(lds_cb + r * 128 + ((j8 ^ (r & 7)) * 16)) = pk;
    }

    // ---- convert chunk0 -> af + ||x||^2; xv regs die here ----
    AFrag af;
    float xn = 0.f;
    #pragma unroll
    for (int kf = 0; kf < 2; ++kf)
        #pragma unroll
        for (int j = 0; j < 8; ++j) {
            const f32x4 v = xv[kf * 8 + j];
            xn = fmaf(v[0], v[0], xn);
            xn = fmaf(v[1], v[1], xn);
            xn = fmaf(v[2], v[2], xn);
            xn = fmaf(v[3], v[3], xn);
            af.a[0][kf][j] = (short)f32_bf16(v[0]);
            af.a[1][kf][j] = (short)f32_bf16(v[1]);
            af.a[2][kf][j] = (short)f32_bf16(v[2]);
            af.a[3][kf][j] = (short)f32_bf16(v[3]);
        }

    __syncthreads();   // drains chunk0+cb loads; codebook + norms resident

    // ---- issue chunk1 loads NOW (reuse xv regs): they stream under
    // scan0 + epi0. sched_barrier pins the issue point (no sinking). ----
    #pragma unroll
    for (int kf = 0; kf < 2; ++kf)
        #pragma unroll
        for (int j = 0; j < 8; ++j)
            xv[kf * 8 + j] = *(const f32x4*)(
                xb + (size_t)(kf * 32 + g * 8 + j) * THW + pos0 + 256);
    __builtin_amdgcn_sched_barrier(0);

    // ---- chunk0 scan + argmin + q stores (hides chunk1 HBM stream) ----
    float* oq0 = out + (size_t)b * (NCH * THW) + rbase + tid;
    float sd = scan_chunk(af, lds_cb, lds_norm, lds_idx, cb,
                          oq0, w, g, r15, tid);

    // ---- convert chunk1 (vmcnt wait lands here) ----
    #pragma unroll
    for (int kf = 0; kf < 2; ++kf)
        #pragma unroll
        for (int j = 0; j < 8; ++j) {
            const f32x4 v = xv[kf * 8 + j];
            xn = fmaf(v[0], v[0], xn);
            xn = fmaf(v[1], v[1], xn);
            xn = fmaf(v[2], v[2], xn);
            xn = fmaf(v[3], v[3], xn);
            af.a[0][kf][j] = (short)f32_bf16(v[0]);
            af.a[1][kf][j] = (short)f32_bf16(v[1]);
            af.a[2][kf][j] = (short)f32_bf16(v[2]);
            af.a[3][kf][j] = (short)f32_bf16(v[3]);
        }

    // ---- chunk1 scan + argmin + q stores (store burst of chunk0 drains
    // under this scan) ----
    sd += scan_chunk(af, lds_cb, lds_norm, lds_idx, cb,
                     oq0 + 256, w, g, r15, tid);

    // ---- per-wave loss partial: sum(||x||^2) + sum(d_best)/16 ----
    float part = fmaf(sd, 0.0625f, xn);
    #pragma unroll
    for (int off = 32; off; off >>= 1) part += __shfl_down(part, off);
    if (lane == 0) partials[blk * 4 + w] = part;
}

__global__ void vq_finalize(const float* __restrict__ partials,
                            float* __restrict__ out) {
    const int tid = threadIdx.x;   // 256 threads, 1024 partials, fixed order
    float v = 0.f;
    #pragma unroll
    for (int k = 0; k < 4; ++k) v += partials[tid + 256 * k];
    #pragma unroll
    for (int off = 32; off; off >>= 1) v += __shfl_down(v, off);
    __shared__ float ws[4];
    if ((tid & 63) == 0) ws[tid >> 6] = v;
    __syncthreads();
    if (tid == 0) {
        const float total  = (ws[0] + ws[1]) + (ws[2] + ws[3]);
        const float commit = total * (1.0f / (float)NELEM);
        out[NELEM]     = 0.25f * commit;   // vq_loss
        out[NELEM + 1] = commit;           // commitment_loss
    }
}

extern "C" void kernel_launch(void* const* d_in, const int* in_sizes, int n_in,
                              void* d_out, int out_size, void* d_ws, size_t ws_size,
                              hipStream_t stream) {
    const float* x  = (const float*)d_in[0];
    const float* cb = (const float*)d_in[1];
    float* out      = (float*)d_out;
    float* partials = (float*)d_ws;        // 1024 floats

    vq_main<<<NBLK, 256, 0, stream>>>(x, cb, out, partials);
    vq_finalize<<<1, 256, 0, stream>>>(partials, out);
}

// Round 7
// 41.978 us; speedup vs baseline: 1.5547x; 1.5547x over previous
//
#include <hip/hip_runtime.h>

// VQ-VAE quantizer forward — R17: barrier-free scan, prepacked codebook.
//   inputs  [B=8, C=64, T=16, H=32, W=32] fp32   (layout: b*C*THW + c*THW + r)
//   codebook[K=512, C=64] fp32
// outputs: q_z [B,C,T,H,W] fp32, vq_loss, commitment_loss (concat flat)
//
// dist(p,k) = ||e_k||^2 - 2*x_p.e_k. MFMA C-init = ||e||^2 => acc IS the
// distance. 9-bit code packed into mantissa LSBs => argmin is pure f32 min.
// Loss via ||e-x||^2 = ||x||^2 + d_best.
//
// Evidence through R16: intra-block pipelining via live prefetch regs spills
// (R13b/R16: VGPR 256, WRITE 85MB); per-block fences poison L2 (R15); the
// R12 body runs ~24us at VGPR 88 / occ 15% / MfmaUtil 6% / VALU 15% — pure
// latency-bound lockstep. R15 FETCH=17MB < x's 33.5MB => x is L3-resident.
//
// R17 removes the lockstep itself:
//  - vq_prep (tiny): prepack bf16(-2e) codebook into SCAN-READY fragment
//    order in ws: per f-block of 16 codes: 64 lanes x 32B contiguous
//    (b0|b1 fragments) + 16 fp32 norms. 67.6 KB total, L2-resident.
//  - vq_main: NO LDS codebook, NO build phase, NO __syncthreads. Each wave
//    streams B-fragments from global (L1/L2-hot: every wave reads the same
//    66 KB; ~135 MB L2 traffic total ~ 4us, fully overlapped). 1024 blocks
//    x 128 thr: finer grain, waves fully decoupled; launch_bounds(128,4)
//    caps VGPR at 128 (natural ~100).
//  - x loads cached f32x4 (L3-resident; 256B segments). q stores NT (exact).
//  - loss via per-wave partials + separate trivial finalize (fence-free).

#define K_CODES 512
#define NCH     64
#define THW     16384
#define NELEM   8388608
#define NBLK    1024
#define PBUF_FSTRIDE 2112                  // per f: 2048B frags + 64B norms
#define PBUF_BYTES   (32 * PBUF_FSTRIDE)   // 67584
#define PART_OFF     (PBUF_BYTES / 4)      // float offset of partials in ws

typedef __attribute__((ext_vector_type(8))) short bf16x8;
typedef __attribute__((ext_vector_type(4))) float f32x4;

__device__ __forceinline__ unsigned short f32_bf16(float f) {
    unsigned u = __float_as_uint(f);
    u += 0x7FFFu + ((u >> 16) & 1u);          // round-to-nearest-even
    return (unsigned short)(u >> 16);
}

// Prepack codebook: fragment layout pbuf[f*2112 + l*32 + {0..15=b0,16..31=b1}]
// where l=(g,r15): b0 = bf16(-2*cb[f*16+r15][g*8+j]), b1 = ch 32+g*8+j.
// Norms at pbuf[f*2112 + 2048 + r15*4] = ||e_{f*16+r15}||^2 (fp32).
__global__ void vq_prep(const float* __restrict__ cb,
                        unsigned char* __restrict__ pbuf) {
    const int t = blockIdx.x * 256 + threadIdx.x;
    if (t < 2048) {
        const int f = t >> 6, l = t & 63;
        const int g = l >> 4, r15 = l & 15;
        const float* cr = cb + (f * 16 + r15) * NCH;
        bf16x8 p0, p1;
        #pragma unroll
        for (int j = 0; j < 8; ++j) {
            p0[j] = (short)f32_bf16(-2.f * cr[g * 8 + j]);
            p1[j] = (short)f32_bf16(-2.f * cr[32 + g * 8 + j]);
        }
        *(bf16x8*)(pbuf + f * PBUF_FSTRIDE + l * 32)      = p0;
        *(bf16x8*)(pbuf + f * PBUF_FSTRIDE + l * 32 + 16) = p1;
    } else if (t < 2560) {
        const int r = t - 2048;
        const float* cr = cb + r * NCH;
        float s = 0.f;
        #pragma unroll
        for (int j = 0; j < 64; ++j) s = fmaf(cr[j], cr[j], s);
        *(float*)(pbuf + (r >> 4) * PBUF_FSTRIDE + 2048 + (r & 15) * 4) = s;
    }
}

__global__ __launch_bounds__(128, 4) void vq_main(
        const float* __restrict__ x,
        const float* __restrict__ cb,
        const unsigned char* __restrict__ pbuf,
        float* __restrict__ out,
        float* __restrict__ partials) {
    __shared__ int lds_idx[128];

    const int tid  = threadIdx.x;
    const int lane = tid & 63;
    const int w    = tid >> 6;       // wave 0..1
    const int g    = lane >> 4;      // 16-lane group 0..3
    const int r15  = lane & 15;

    const int blk   = blockIdx.x;
    const int b     = blk >> 7;                 // batch (128 blocks per batch)
    const int rblk  = (blk & 127) << 7;         // 128 positions per block
    const float* xb = x + (size_t)b * (NCH * THW);
    const int pos0  = rblk + w * 64 + 4 * r15;  // lane's base position

    // ---- x loads: f32x4; 16 lanes x 16B = 256B contiguous (L3-resident) ----
    // lane(g,r15) gets positions {pos0+tt, tt=0..3} of channel kf*32+g*8+j
    f32x4 xv[16];
    #pragma unroll
    for (int kf = 0; kf < 2; ++kf)
        #pragma unroll
        for (int j = 0; j < 8; ++j)
            xv[kf * 8 + j] = *(const f32x4*)(
                xb + (size_t)(kf * 32 + g * 8 + j) * THW + pos0);

    // ---- convert -> bf16 A-frags + fp32 ||x||^2 partial ----
    bf16x8 af[4][2];   // [tile tt][K-half]
    float  xn = 0.f;
    #pragma unroll
    for (int kf = 0; kf < 2; ++kf)
        #pragma unroll
        for (int j = 0; j < 8; ++j) {
            const f32x4 v = xv[kf * 8 + j];
            xn = fmaf(v[0], v[0], xn);
            xn = fmaf(v[1], v[1], xn);
            xn = fmaf(v[2], v[2], xn);
            xn = fmaf(v[3], v[3], xn);
            af[0][kf][j] = (short)f32_bf16(v[0]);
            af[1][kf][j] = (short)f32_bf16(v[1]);
            af[2][kf][j] = (short)f32_bf16(v[2]);
            af[3][kf][j] = (short)f32_bf16(v[3]);
        }

    // ---- scan all 512 codes; B-fragments streamed from global (L1/L2-hot),
    // per f: 64 lanes x 32B = 2KB contiguous + 64B norm row. NO barrier. ----
    float best[4][4];
    #pragma unroll
    for (int tt = 0; tt < 4; ++tt)
        #pragma unroll
        for (int i = 0; i < 4; ++i) best[tt][i] = 3.4e38f;

    const unsigned char* pl = pbuf + lane * 32;
    #pragma unroll 4
    for (int f = 0; f < 32; ++f) {
        const bf16x8 b0 = *(const bf16x8*)(pl + f * PBUF_FSTRIDE);
        const bf16x8 b1 = *(const bf16x8*)(pl + f * PBUF_FSTRIDE + 16);
        const float nrm = *(const float*)(pbuf + f * PBUF_FSTRIDE + 2048 + r15 * 4);
        const unsigned code = (unsigned)(f * 16 + r15);   // lane's B-column
        #pragma unroll
        for (int tt = 0; tt < 4; ++tt) {
            f32x4 acc = {nrm, nrm, nrm, nrm};
            acc = __builtin_amdgcn_mfma_f32_16x16x32_bf16(af[tt][0], b0, acc, 0, 0, 0);
            acc = __builtin_amdgcn_mfma_f32_16x16x32_bf16(af[tt][1], b1, acc, 0, 0, 0);
            #pragma unroll
            for (int i = 0; i < 4; ++i) {   // acc[i]: pos pos0 - 4*r15 + 4*(4g+i) + tt
                const float pkv = __uint_as_float(
                    (__float_as_uint(acc[i]) & ~511u) | code);
                best[tt][i] = fminf(best[tt][i], pkv);
            }
        }
    }

    // ---- wave-local argmin (reduce over r15 = code axis) ----
    float sd = 0.f;
    int   idxs[4][4];
    #pragma unroll
    for (int tt = 0; tt < 4; ++tt) {
        #pragma unroll
        for (int i = 0; i < 4; ++i) {
            float v = best[tt][i];
            #pragma unroll
            for (int off = 8; off; off >>= 1) v = fminf(v, __shfl_xor(v, off));
            sd += v;                                // replicated x16 per group
            idxs[tt][i] = (int)(__float_as_uint(v) & 511u);
        }
    }
    if (r15 == 0) {                   // same-wave RAW only (no barrier needed)
        #pragma unroll
        for (int tt = 0; tt < 4; ++tt)
            #pragma unroll
            for (int i = 0; i < 4; ++i)
                lds_idx[w * 64 + 16 * g + 4 * i + tt] = idxs[tt][i];
    }
    // per-wave loss partial: sum(||x||^2) + sum(d_best)/16
    float part = fmaf(sd, 0.0625f, xn);
    #pragma unroll
    for (int off = 32; off; off >>= 1) part += __shfl_down(part, off);
    if (lane == 0) partials[blk * 2 + w] = part;

    // ---- epilogue: lane = one position; q from fp32 cb (L2-hot); NT stores
    const int bc = lds_idx[tid];                       // tid == w*64 + lane
    float* oq = out + (size_t)b * (NCH * THW) + (rblk + tid);
    const f32x4* crow = (const f32x4*)(cb + (size_t)bc * NCH);
    #pragma unroll
    for (int jj = 0; jj < 16; ++jj) {
        const f32x4 e = crow[jj];
        const size_t c0 = (size_t)(jj * 4) * THW;
        __builtin_nontemporal_store(e[0], oq + c0);
        __builtin_nontemporal_store(e[1], oq + c0 + THW);
        __builtin_nontemporal_store(e[2], oq + c0 + 2 * THW);
        __builtin_nontemporal_store(e[3], oq + c0 + 3 * THW);
    }
}

__global__ void vq_finalize(const float* __restrict__ partials,
                            float* __restrict__ out) {
    const int tid = threadIdx.x;   // 256 threads, 2048 partials, fixed order
    float v = 0.f;
    #pragma unroll
    for (int k = 0; k < 8; ++k) v += partials[tid + 256 * k];
    #pragma unroll
    for (int off = 32; off; off >>= 1) v += __shfl_down(v, off);
    __shared__ float ws[4];
    if ((tid & 63) == 0) ws[tid >> 6] = v;
    __syncthreads();
    if (tid == 0) {
        const float total  = (ws[0] + ws[1]) + (ws[2] + ws[3]);
        const float commit = total * (1.0f / (float)NELEM);
        out[NELEM]     = 0.25f * commit;   // vq_loss
        out[NELEM + 1] = commit;           // commitment_loss
    }
}

extern "C" void kernel_launch(void* const* d_in, const int* in_sizes, int n_in,
                              void* d_out, int out_size, void* d_ws, size_t ws_size,
                              hipStream_t stream) {
    const float* x  = (const float*)d_in[0];
    const float* cb = (const float*)d_in[1];
    float* out      = (float*)d_out;
    unsigned char* pbuf = (unsigned char*)d_ws;        // 67584 B prepack
    float* partials = (float*)d_ws + PART_OFF;         // 2048 floats after

    vq_prep<<<10, 256, 0, stream>>>(cb, pbuf);
    vq_main<<<NBLK, 128, 0, stream>>>(x, cb, pbuf, out, partials);
    vq_finalize<<<1, 256, 0, stream>>>(partials, out);
}

// Round 8
// 27.530 us; speedup vs baseline: 2.3705x; 1.5248x over previous
//
#include <hip/hip_runtime.h>

// VQ-VAE quantizer forward — R18: prepacked codebook + global_load_lds DMA.
//   inputs  [B=8, C=64, T=16, H=32, W=32] fp32   (layout: b*C*THW + c*THW + r)
//   codebook[K=512, C=64] fp32
// outputs: q_z [B,C,T,H,W] fp32, vq_loss, commitment_loss (concat flat)
//
// dist(p,k) = ||e_k||^2 - 2*x_p.e_k. MFMA C-init = ||e||^2 => acc IS the
// distance. 9-bit code packed into mantissa LSBs => argmin is pure f32 min.
// Loss via ||e-x||^2 = ||x||^2 + d_best.
//
// Evidence: R12/R15 body = 24us @ VGPR 88, WRITE exact, occ 15%, Mfma 6% —
// latency-bound lockstep; scan must eat from LDS (R17: global-B scan = 41us).
// Register prefetch pipelining spills (R13b/R16); per-block fences poison L2
// (R15). The remaining removable serial phase is the per-block codebook
// build: 512 blocks x (128KB fp32 reads + ~2.2k cyc convert/shuffle VALU).
//
// R18: vq_prep builds the EXACT 67,584-B LDS image once in ws (65,536B
// swizzled bf16(-2e) cb + 2,048B fp32 norms). vq_main's build phase becomes
// 17 global_load_lds dwordx4 rounds (wave-uniform LDS dest, linear src — the
// layout constraint global_load_lds requires), zero VALU, overlapped with x
// loads. Scan/argmin/epilogue byte-identical to R15's proven body. Fence-free
// separate finalize.

#define K_CODES 512
#define NCH     64
#define THW     16384
#define NELEM   8388608
#define NBLK    512
#define IMG_BYTES 67584                    // 65536 cb + 2048 norms
#define PART_OFF  (IMG_BYTES / 4)          // float offset of partials in ws

typedef __attribute__((ext_vector_type(8))) short bf16x8;
typedef __attribute__((ext_vector_type(4))) float f32x4;

__device__ __forceinline__ unsigned short f32_bf16(float f) {
    unsigned u = __float_as_uint(f);
    u += 0x7FFFu + ((u >> 16) & 1u);          // round-to-nearest-even
    return (unsigned short)(u >> 16);
}

// Build the LDS image: byte r*128 + ((j8^(r&7))*16) = bf16(-2*cb[r][j8*8..+8)),
// byte 65536 + r*4 = ||e_r||^2 (fp32). Same layout R12's in-block build made.
__global__ void vq_prep(const float* __restrict__ cb,
                        unsigned char* __restrict__ pbuf) {
    const int t = blockIdx.x * 256 + threadIdx.x;
    if (t < 4096) {                       // 512 rows x 8 chunks
        const int r  = t >> 3;
        const int j8 = t & 7;
        const f32x4* cr = (const f32x4*)(cb + r * NCH + j8 * 8);
        const f32x4 e0 = cr[0];
        const f32x4 e1 = cr[1];
        bf16x8 pk;
        pk[0] = (short)f32_bf16(-2.f * e0[0]);
        pk[1] = (short)f32_bf16(-2.f * e0[1]);
        pk[2] = (short)f32_bf16(-2.f * e0[2]);
        pk[3] = (short)f32_bf16(-2.f * e0[3]);
        pk[4] = (short)f32_bf16(-2.f * e1[0]);
        pk[5] = (short)f32_bf16(-2.f * e1[1]);
        pk[6] = (short)f32_bf16(-2.f * e1[2]);
        pk[7] = (short)f32_bf16(-2.f * e1[3]);
        *(bf16x8*)(pbuf + r * 128 + ((j8 ^ (r & 7)) * 16)) = pk;
    } else if (t < 4608) {                // 512 norms
        const int r = t - 4096;
        const f32x4* cr = (const f32x4*)(cb + r * NCH);
        float s = 0.f;
        #pragma unroll
        for (int jj = 0; jj < 16; ++jj) {
            const f32x4 e = cr[jj];
            s = fmaf(e[0], e[0], s);
            s = fmaf(e[1], e[1], s);
            s = fmaf(e[2], e[2], s);
            s = fmaf(e[3], e[3], s);
        }
        *(float*)(pbuf + 65536 + r * 4) = s;
    }
}

__global__ __launch_bounds__(256, 2) void vq_main(
        const float* __restrict__ x,
        const float* __restrict__ cb,
        const unsigned char* __restrict__ pbuf,
        float* __restrict__ out,
        float* __restrict__ partials) {
    __shared__ __align__(16) unsigned char lds_img[IMG_BYTES];
    __shared__ int lds_idx[256];

    const int tid  = threadIdx.x;
    const int lane = tid & 63;
    const int w    = tid >> 6;       // wave 0..3
    const int g    = lane >> 4;      // 16-lane group 0..3
    const int r15  = lane & 15;

    const int blk  = blockIdx.x;
    const int b    = blk >> 6;                 // batch (64 blocks per batch)
    const int rblk = (blk & 63) << 8;          // 256 positions per block
    const int rw   = rblk + w * 64;            // wave's first position
    const float* xb = x + (size_t)b * (NCH * THW);

    // ---- DMA the prepacked image into LDS: 16 cb rounds + 1 norm round.
    // global_load_lds: per-lane global src, wave-uniform LDS base + lane*16.
    // Per round each wave moves 1024B; layout is linear (swizzle pre-applied
    // in pbuf), satisfying the contiguous-dest constraint. Zero VALU. ----
    {
        const int lbase = w * 1024 + lane * 16;
        #pragma unroll
        for (int r = 0; r < 16; ++r) {
            __builtin_amdgcn_global_load_lds(
                (__attribute__((address_space(1))) const void*)(pbuf + r * 4096 + lbase),
                (__attribute__((address_space(3))) void*)(lds_img + r * 4096 + w * 1024),
                16, 0, 0);
        }
        if (w < 2)   // norms: 2048B = 2 wave-rounds (wave-uniform predicate)
            __builtin_amdgcn_global_load_lds(
                (__attribute__((address_space(1))) const void*)(pbuf + 65536 + lbase),
                (__attribute__((address_space(3))) void*)(lds_img + 65536 + w * 1024),
                16, 0, 0);
    }

    // ---- x loads: f32x4; 16 lanes x 16B = 256B contiguous (overlap DMA) ----
    // lane(g,r15) gets positions {rw+4*r15+tt, tt=0..3} of channel kf*32+g*8+j
    f32x4 xv[2][8];
    #pragma unroll
    for (int kf = 0; kf < 2; ++kf)
        #pragma unroll
        for (int j = 0; j < 8; ++j)
            xv[kf][j] = *(const f32x4*)(xb + (size_t)(kf * 32 + g * 8 + j) * THW
                                           + rw + 4 * r15);

    // ---- convert x to bf16 A-frags + fp32 ||x||^2 partial ----
    bf16x8 af[4][2];
    float  xn = 0.f;
    #pragma unroll
    for (int kf = 0; kf < 2; ++kf)
        #pragma unroll
        for (int j = 0; j < 8; ++j) {
            const f32x4 v = xv[kf][j];
            xn = fmaf(v[0], v[0], xn);
            xn = fmaf(v[1], v[1], xn);
            xn = fmaf(v[2], v[2], xn);
            xn = fmaf(v[3], v[3], xn);
            af[0][kf][j] = (short)f32_bf16(v[0]);
            af[1][kf][j] = (short)f32_bf16(v[1]);
            af[2][kf][j] = (short)f32_bf16(v[2]);
            af[3][kf][j] = (short)f32_bf16(v[3]);
        }

    __syncthreads();   // drains DMA (vmcnt) — codebook + norms resident

    // ---- scan all 512 codes (identical to R12/R15 proven body) ----
    float best[4][4];
    #pragma unroll
    for (int tt = 0; tt < 4; ++tt)
        #pragma unroll
        for (int i = 0; i < 4; ++i) best[tt][i] = 3.4e38f;

    const int swz = (r15 & 7) << 4;
    const unsigned char* pb0 = lds_img + r15 * 128 + ((g * 16) ^ swz);
    const unsigned char* pb1 = lds_img + r15 * 128 + ((64 + g * 16) ^ swz);
    const float* lds_norm = (const float*)(lds_img + 65536);
    #pragma unroll
    for (int f = 0; f < 32; ++f) {
        const bf16x8 b0 = *(const bf16x8*)(pb0 + f * 2048);
        const bf16x8 b1 = *(const bf16x8*)(pb1 + f * 2048);
        const float nrm = lds_norm[f * 16 + r15];
        const unsigned code = (unsigned)(f * 16 + r15);   // lane's B-column
        #pragma unroll
        for (int tt = 0; tt < 4; ++tt) {
            f32x4 acc = {nrm, nrm, nrm, nrm};
            acc = __builtin_amdgcn_mfma_f32_16x16x32_bf16(af[tt][0], b0, acc, 0, 0, 0);
            acc = __builtin_amdgcn_mfma_f32_16x16x32_bf16(af[tt][1], b1, acc, 0, 0, 0);
            #pragma unroll
            for (int i = 0; i < 4; ++i) {   // acc[i]: pos rw+4*(4g+i)+tt
                const float pkv = __uint_as_float(
                    (__float_as_uint(acc[i]) & ~511u) | code);
                best[tt][i] = fminf(best[tt][i], pkv);
            }
        }
    }

    // ---- wave-local argmin (reduce over r15 = code axis) ----
    float sd = 0.f;
    int   idxs[4][4];
    #pragma unroll
    for (int tt = 0; tt < 4; ++tt) {
        #pragma unroll
        for (int i = 0; i < 4; ++i) {
            float v = best[tt][i];
            #pragma unroll
            for (int off = 8; off; off >>= 1) v = fminf(v, __shfl_xor(v, off));
            sd += v;                                // replicated x16 per group
            idxs[tt][i] = (int)(__float_as_uint(v) & 511u);
        }
    }
    if (r15 == 0) {                   // same-wave RAW only (no barrier needed)
        #pragma unroll
        for (int tt = 0; tt < 4; ++tt)
            #pragma unroll
            for (int i = 0; i < 4; ++i)
                lds_idx[w * 64 + 16 * g + 4 * i + tt] = idxs[tt][i];
    }
    // per-wave loss partial: sum(||x||^2) + sum(d_best)/16
    float part = fmaf(sd, 0.0625f, xn);
    #pragma unroll
    for (int off = 32; off; off >>= 1) part += __shfl_down(part, off);
    if (lane == 0) partials[blk * 4 + w] = part;

    // ---- epilogue: lane = one position; q from fp32 cb (L2-hot); NT stores
    const int bc = lds_idx[tid];                       // tid == w*64 + lane
    float* oq = out + (size_t)b * (NCH * THW) + (rblk + tid);
    const f32x4* crow = (const f32x4*)(cb + (size_t)bc * NCH);
    #pragma unroll
    for (int jj = 0; jj < 16; ++jj) {
        const f32x4 e = crow[jj];
        const size_t c0 = (size_t)(jj * 4) * THW;
        __builtin_nontemporal_store(e[0], oq + c0);
        __builtin_nontemporal_store(e[1], oq + c0 + THW);
        __builtin_nontemporal_store(e[2], oq + c0 + 2 * THW);
        __builtin_nontemporal_store(e[3], oq + c0 + 3 * THW);
    }
}

__global__ void vq_finalize(const float* __restrict__ partials,
                            float* __restrict__ out) {
    const int tid = threadIdx.x;   // 256 threads, 2048 partials, fixed order
    float v = 0.f;
    #pragma unroll
    for (int k = 0; k < 8; ++k) v += partials[tid + 256 * k];
    #pragma unroll
    for (int off = 32; off; off >>= 1) v += __shfl_down(v, off);
    __shared__ float ws[4];
    if ((tid & 63) == 0) ws[tid >> 6] = v;
    __syncthreads();
    if (tid == 0) {
        const float total  = (ws[0] + ws[1]) + (ws[2] + ws[3]);
        const float commit = total * (1.0f / (float)NELEM);
        out[NELEM]     = 0.25f * commit;   // vq_loss
        out[NELEM + 1] = commit;           // commitment_loss
    }
}

extern "C" void kernel_launch(void* const* d_in, const int* in_sizes, int n_in,
                              void* d_out, int out_size, void* d_ws, size_t ws_size,
                              hipStream_t stream) {
    const float* x  = (const float*)d_in[0];
    const float* cb = (const float*)d_in[1];
    float* out      = (float*)d_out;
    unsigned char* pbuf = (unsigned char*)d_ws;    // 67,584 B LDS image
    float* partials = (float*)d_ws + PART_OFF;     // 2048 floats after image

    vq_prep<<<18, 256, 0, stream>>>(cb, pbuf);
    vq_main<<<NBLK, 256, 0, stream>>>(x, cb, pbuf, out, partials);
    vq_finalize<<<1, 256, 0, stream>>>(partials, out);
}